// Round 14
// baseline (201.203 us; speedup 1.0000x reference)
//
#include <hip/hip_runtime.h>
#include <hip/hip_bf16.h>
#include <math.h>

#define NEGV -1e30f
#define LN2F 0.6931471805599453f

// B=16, T=800, D=512, V=4000 (padded to 4096), Lmax=100, S=201
// M = B*T = 12800 rows.
// GEMM operands are stored PRE-SWIZZLED in MFMA fragment order:
//   A2[rb<100][it<16][wm<2][mi<4][lane<64][8]  (row = rb*128+wm*64+mi*16+(lane&15), k = it*32+(lane>>4)*8)
//   W2[ct<32][it<16][wn<2][ni<4][lane<64][8]   (col = ct*128+wn*64+ni*16+(lane&15), same k)
// Each (tile, K-step) chunk is a contiguous 8 KB block -> LDS staging is a
// linear global_load_lds copy and fragment reads are conflict-free ds_read_b128.

typedef __attribute__((ext_vector_type(8))) short bf16x8;
typedef __attribute__((ext_vector_type(4))) float f32x4;

__device__ __forceinline__ short f2bf(float x) {
    __hip_bfloat16 h = __float2bfloat16(x);
    return __builtin_bit_cast(short, h);
}

// wave-wide shift-up-by-1 with zero fill on the VALU (DPP wave_shr:1)
__device__ __forceinline__ float shup1(float x) {
    return __builtin_bit_cast(float,
        __builtin_amdgcn_update_dpp(0, __builtin_bit_cast(int, x),
                                    0x138, 0xf, 0xf, true));
}

#define GLD_LDS(g, l) \
    __builtin_amdgcn_global_load_lds( \
        (const __attribute__((address_space(1))) void*)(g), \
        (__attribute__((address_space(3))) void*)(l), 16, 0, 0)

// inline-asm global load into named registers; draining controlled by WAITV
#define LOADX4(dst, addr, off) \
    asm volatile("global_load_dwordx4 %0, %1, off offset:" #off \
                 : "=&v"(dst) : "v"(addr) : "memory")

// counted drain + full scheduling fence (rule #18)
#define WAITV(n) do { \
    asm volatile("s_waitcnt vmcnt(" #n ")" ::: "memory"); \
    __builtin_amdgcn_sched_barrier(0); \
} while (0)

// ---------------------------------------------------------------------------
// prep (R13-proven): monolithic, 16-way-parallel table setup.
// blocks 0..1023 W-swizzle; 1024..4223 A-swizzle; 4224..4239 per-batch
// tables; 4240 biasp/lse_sum/out init. grid 4241 x 256.
// ---------------------------------------------------------------------------
__global__ __launch_bounds__(256) void prep(
    const float* __restrict__ hs, const float* __restrict__ W,
    const float* __restrict__ bias, const int* __restrict__ ys,
    short* __restrict__ W2, short* __restrict__ A2,
    float* __restrict__ biasp, unsigned char* __restrict__ M,
    unsigned char* __restrict__ canon, float* __restrict__ lse_sum,
    float* __restrict__ out)
{
    __shared__ float tile[32][65];
    __shared__ unsigned char mapl[4096];
    const int bx = blockIdx.x, tid = threadIdx.x;

    if (bx < 1024) {
        // ---- W [512][4000] -> W2 fragment layout (zero-pad cols>=4000) ----
        const int n0 = (bx & 63) * 64;     // 64-col group
        const int k0 = (bx >> 6) * 32;     // 32-k group
        #pragma unroll
        for (int p = 0; p < 8; p++) {
            int idx = p * 256 + tid;
            int k = idx >> 6, n = idx & 63;
            int gn = n0 + n;
            tile[k][n] = (gn < 4000) ? W[(size_t)(k0 + k) * 4000 + gn] : 0.0f;
        }
        __syncthreads();
        const int nn = tid >> 6, lane = tid & 63;
        const int l16 = lane & 15, quad = lane >> 4;
        const int ct = n0 >> 7, wn = (n0 >> 6) & 1, it = k0 >> 5;
        size_t chunk = ((((size_t)ct * 16 + it) * 2 + wn) * 4 + nn) * 64 + lane;
        bf16x8 r;
        #pragma unroll
        for (int j = 0; j < 8; j++) r[j] = f2bf(tile[quad * 8 + j][nn * 16 + l16]);
        *(bf16x8*)(W2 + chunk * 8) = r;
    } else if (bx < 4224) {
        // ---- hs fp32 -> A2 fragment layout ----
        int g = (bx - 1024) * 256 + tid;           // 0..819199
        int lane = g & 63, mi = (g >> 6) & 3, wm = (g >> 8) & 1;
        int it = (g >> 9) & 15, rb = g >> 13;
        int row = rb * 128 + wm * 64 + mi * 16 + (lane & 15);
        int k = it * 32 + (lane >> 4) * 8;
        const float* src = hs + (size_t)row * 512 + k;
        float4 u = *(const float4*)src;
        float4 v = *(const float4*)(src + 4);
        bf16x8 r;
        r[0] = f2bf(u.x); r[1] = f2bf(u.y); r[2] = f2bf(u.z); r[3] = f2bf(u.w);
        r[4] = f2bf(v.x); r[5] = f2bf(v.y); r[6] = f2bf(v.z); r[7] = f2bf(v.w);
        *(bf16x8*)(A2 + (size_t)g * 8) = r;
    } else if (bx < 4240) {
        // ---- tables for batch b = bx - 4224 (16-way parallel) ----
        const int b = bx - 4224;
        for (int i = tid; i < 1024; i += 256)
            ((unsigned int*)mapl)[i] = 0xFFFFFFFFu;
        __syncthreads();
        if (tid == 0) mapl[0] = 0;
        __syncthreads();
        if (tid < 100) mapl[ys[b * 100 + tid]] = (unsigned char)(tid + 1);
        __syncthreads();
        for (int i = tid; i < 1024; i += 256)
            ((unsigned int*)(M + (size_t)b * 4096))[i] = ((const unsigned int*)mapl)[i];
        if (tid < 128) {
            int colc = (tid >= 1 && tid <= 100) ? ys[b * 100 + tid - 1] : 0;
            canon[b * 128 + tid] = mapl[colc];
        }
    } else {
        // ---- biasp / lse_sum / out init ----
        for (int i = tid; i < 4096; i += 256)
            biasp[i] = (i < 4000) ? bias[i] : NEGV;
        for (int i = tid; i < 12800; i += 256)
            lse_sum[i] = 0.0f;
        if (tid == 0) out[0] = 0.0f;
    }
}

// ---------------------------------------------------------------------------
// Streaming-sumexp GEMM. R14: HYBRID operand routing — A staged in LDS
// (reused by 4 column-waves), B loaded DIRECTLY from global into registers
// (wave-private bf[4], 2 named sets, counted vmcnt). Removes B's LDS
// write+read: LDS/CU/K-step-pair 88 -> 40 KB, stage 8 KB/chunk (1 load/wave).
// Queue order per iter: LOADB(it+1) BEFORE STAGE(it+2), so WAITV(1) retires
// {stage(it+1), B(it+1)} and leaves stage(it+2) in flight. 16-barrier
// skeleton unchanged. LDS 24 KB, 2 blocks/CU. grid 1664 x 512.
// ---------------------------------------------------------------------------
__global__ __launch_bounds__(512, 4) void lse_mfma(
    const short* __restrict__ A2,     // fragment layout
    const short* __restrict__ W2,     // fragment layout
    const float* __restrict__ biasp,  // [4096]
    const unsigned char* __restrict__ M,  // [16][4096]
    float* __restrict__ lse_sum,      // [12800]
    __hip_bfloat16* __restrict__ Praw)// [12800][128]
{
    const unsigned int bid = blockIdx.x;
    const unsigned int xcd = bid & 7;
    const unsigned int s = bid >> 3;       // 0..207
    const unsigned int cp = s / 13;        // 0..15  (slow: 256-col tile)
    const unsigned int rl = s - cp * 13;   // 0..12  (fast: row tile within XCD)
    const unsigned int rb = rl * 8 + xcd;  // 0..103
    if (rb >= 100) return;

    const int tid = threadIdx.x;
    const int w = tid >> 6, lane = tid & 63;   // w = 0..7
    const int quad = lane >> 4, l16 = lane & 15;
    const int wm = w >> 2;                 // 0..1: 64-row half
    const int wc = w & 3;                  // 0..3: 64-col slot
    const int row0 = rb * 128;
    const int col0 = cp * 256;

    // 3 rotating A-staging buffers: 4096 shorts (8 KB) each
    __shared__ __align__(16) short sbuf[3][4096];

    // A staging: 8 x 1-KB segments; wave w owns segment w (lane-linear).
    const short* gA = A2 + (size_t)rb * 65536 + w * 512 + lane * 8;
    const int loA = w * 512 + lane * 8;

#define STAGE(s_, bi_) GLD_LDS(gA + (size_t)(s_) * 4096, &sbuf[bi_][loA])

    // B direct-load base: wave's 64-col slice of the 256-col tile
    const short* Bgl = W2 + (size_t)(2 * cp + (wc >> 1)) * 65536
                          + (wc & 1) * 2048 + lane * 8;

#define LOADB(it_, bf_) do { \
    const short* _b = Bgl + (size_t)(it_) * 4096; \
    LOADX4(bf_[0], _b, 0);    LOADX4(bf_[1], _b, 1024); \
    LOADX4(bf_[2], _b, 2048); LOADX4(bf_[3], _b, 3072); \
} while (0)

    f32x4 acc[4][4];
    #pragma unroll
    for (int mi = 0; mi < 4; mi++)
        #pragma unroll
        for (int ni = 0; ni < 4; ni++) acc[mi][ni] = (f32x4){0.f,0.f,0.f,0.f};

    bf16x8 bfA[4], bfB[4];      // two named B-register sets (even/odd it)

    STAGE(0, 0);                // queue: st0
    LOADB(0, bfA);              // queue: st0, B0x4
    STAGE(1, 1);                // queue: st0, B0x4, st1
    WAITV(1);                   // drain st0 + B0; st1 in flight
    __builtin_amdgcn_s_barrier();
    __builtin_amdgcn_sched_barrier(0);

    #pragma unroll
    for (int it = 0; it < 16; ++it) {
        // issue next B first (must retire before next iter), then next stage
        if (it + 1 < 16) {
            if ((it + 1) & 1) LOADB(it + 1, bfB);
            else              LOADB(it + 1, bfA);
        }
        if (it + 2 < 16) STAGE(it + 2, (it + 2) % 3);

        const short* ap = &sbuf[it % 3][wm * 2048 + lane * 8];   // + mi*512
        bf16x8 af[4];
        #pragma unroll
        for (int mi = 0; mi < 4; mi++) af[mi] = *(const bf16x8*)(ap + mi * 512);

        __builtin_amdgcn_s_setprio(1);
        if (it & 1) {
            #pragma unroll
            for (int mi = 0; mi < 4; mi++)
                #pragma unroll
                for (int ni = 0; ni < 4; ni++)
                    acc[mi][ni] = __builtin_amdgcn_mfma_f32_16x16x32_bf16(
                        af[mi], bfB[ni], acc[mi][ni], 0, 0, 0);
        } else {
            #pragma unroll
            for (int mi = 0; mi < 4; mi++)
                #pragma unroll
                for (int ni = 0; ni < 4; ni++)
                    acc[mi][ni] = __builtin_amdgcn_mfma_f32_16x16x32_bf16(
                        af[mi], bfA[ni], acc[mi][ni], 0, 0, 0);
        }
        __builtin_amdgcn_s_setprio(0);

        if (it < 15) {
            if (it < 14) { WAITV(1); }  // retire stage(it+1)+B(it+1); stage(it+2) in flight
            else         { WAITV(0); }  // tail: retire stage(15)+B(15)
            __builtin_amdgcn_s_barrier();
            __builtin_amdgcn_sched_barrier(0);
        }
    }
#undef STAGE
#undef LOADB
    __builtin_amdgcn_sched_barrier(0);   // keep epilogue VMEM out of the loop

    // epilogue: sumexp partials + scatter label-column logits
    const int b0i = row0 / 800;
    const int b1i = (b0i + 1 < 16) ? b0i + 1 : 15;
    const int bbound = (b0i + 1) * 800;
    float sv[16];
    #pragma unroll
    for (int i = 0; i < 16; i++) sv[i] = 0.0f;
    #pragma unroll
    for (int ni = 0; ni < 4; ni++) {
        int col = col0 + wc * 64 + ni * 16 + l16;
        float bj = biasp[col];
        unsigned char sl0 = M[(size_t)b0i * 4096 + col];
        unsigned char sl1 = M[(size_t)b1i * 4096 + col];
        #pragma unroll
        for (int mi = 0; mi < 4; mi++) {
            #pragma unroll
            for (int r = 0; r < 4; r++) {
                int row = row0 + wm * 64 + mi * 16 + quad * 4 + r;
                float v = acc[mi][ni][r] + bj;
                sv[mi * 4 + r] += __expf(v);
                unsigned char sl = (row < bbound) ? sl0 : sl1;
                if (sl != 255)
                    Praw[(size_t)row * 128 + sl] = __float2bfloat16(v);
            }
        }
    }
    #pragma unroll
    for (int off = 1; off < 16; off <<= 1)
        #pragma unroll
        for (int i = 0; i < 16; i++) sv[i] += __shfl_xor(sv[i], off);
    if (l16 == 0) {
        #pragma unroll
        for (int mi = 0; mi < 4; mi++)
            #pragma unroll
            for (int r = 0; r < 4; r++)
                atomicAdd(&lse_sum[row0 + wm * 64 + mi * 16 + quad * 4 + r],
                          sv[mi * 4 + r]);
    }
}

// ---------------------------------------------------------------------------
// pexp (R5-proven): PE[row][s] = exp(Praw[row][st[s]]) * rcp(lse) * 2^11.
// 800 blocks -> massive parallelism for the strided gather.
// ---------------------------------------------------------------------------
__global__ __launch_bounds__(256) void pexp(
    const __hip_bfloat16* __restrict__ Praw,  // [12800][128]
    const float* __restrict__ lse_sum,        // [12800]
    const unsigned char* __restrict__ canon,  // [16][128]
    float* __restrict__ PE)                   // [12800][208]
{
    __shared__ unsigned char st[224];
    __shared__ float scs[16];
    const int bp = blockIdx.x;           // 0..799
    const int b = bp / 50, rr = bp - b * 50;
    const int tid = threadIdx.x;
    const unsigned char* cb = canon + b * 128;
    if (tid < 224) {
        int idx = (tid + 1) >> 1;
        st[tid] = (tid & 1) ? cb[idx < 128 ? idx : 127] : (unsigned char)0;
    }
    const int row0 = b * 800 + rr * 16;
    if (tid < 16) scs[tid] = __builtin_amdgcn_rcpf(lse_sum[row0 + tid]) * 2048.0f;
    __syncthreads();
    for (int item = tid; item < 832; item += 256) {   // 16 rows x 52 float4
        int i = item / 52, sg = item - i * 52;
        int row = row0 + i;
        const __hip_bfloat16* pr = Praw + (size_t)row * 128;
        float sc = scs[i];
        int s0 = sg * 4;
        float4 o;
        o.x = (s0 + 0 <= 200) ? __expf(__bfloat162float(pr[st[s0 + 0]])) * sc : 0.f;
        o.y = (s0 + 1 <= 200) ? __expf(__bfloat162float(pr[st[s0 + 1]])) * sc : 0.f;
        o.z = (s0 + 2 <= 200) ? __expf(__bfloat162float(pr[st[s0 + 2]])) * sc : 0.f;
        o.w = (s0 + 3 <= 200) ? __expf(__bfloat162float(pr[st[s0 + 3]])) * sc : 0.f;
        *(float4*)&PE[(size_t)row * 208 + s0] = o;
    }
}

// ---------------------------------------------------------------------------
// ctc_dp (R9-proven): CTC forward DP, 3-buffer rotating PE->LDS staging with
// counted vmcnt, 2 chunks ahead. All global_load_lds full-exec and
// lane-linear (m104 HW rule). Waves 2,3: 17 loads/chunk; wave 1: 18.
// Drains: wave1 WAITV(18), waves2/3 WAITV(17); never 0 until tail.
// ---------------------------------------------------------------------------
__global__ __launch_bounds__(256) void ctc_dp(
    const float* __restrict__ PE,             // [12800][208]
    const int* __restrict__ hlens,
    const int* __restrict__ ys,
    const int* __restrict__ ylens,
    float* __restrict__ out)
{
    const int b = blockIdx.x, tid = threadIdx.x;
    const int w = tid >> 6, lane = tid & 63;
    __shared__ float emS[3][13376];   // 3 x (64 rows x 208 + pad)
    __shared__ float sA[256];

    const float* Pb = PE + (size_t)b * 800 * 208;
    const int hl = hlens[b], L = ylens[b];
    const int t_stop = hl - 1;
    const int C = (t_stop + 63) >> 6;

    const int yb = b * 100;
    float kA = 0.f, kB = 0.f, kH = 0.f;
    if (lane >= 1 && 2 * lane <= 99)
        kA = (ys[yb + 2 * lane] != ys[yb + 2 * lane - 1]) ? 1.f : 0.f;
    if (2 * lane + 1 <= 99)
        kB = (ys[yb + 2 * lane + 1] != ys[yb + 2 * lane]) ? 1.f : 0.f;
    if (lane >= 1 && 2 * lane - 1 <= 99)
        kH = (ys[yb + 2 * lane - 1] != ys[yb + 2 * lane - 2]) ? 1.f : 0.f;
    const float m0  = (lane <= 50) ? 1.f : 0.f;
    const float m13 = (lane <= 49) ? 1.f : 0.f;

    float a0 = 0.f, a1 = 0.f, a2 = 0.f, a3 = 0.f;
    if (w == 0 && lane == 0) {
        a0 = Pb[0];
        a1 = Pb[1];
    }
    int kacc = 0;

    // staging: waves 1-3 (192 threads). All loads full-exec, lane-linear.
#define STAGE_DP(nc_) do { \
    const char* _src = (const char*)(Pb + (size_t)(64 * (nc_) + 1) * 208); \
    char* _dst = (char*)&emS[(nc_) % 3][0]; \
    const int _base = tid - 64; \
    _Pragma("unroll") \
    for (int _j = 0; _j < 17; _j++) { \
        int _idx = _base + 192 * _j; \
        GLD_LDS(_src + (size_t)_idx * 16, _dst + (size_t)_idx * 16); \
    } \
    if (w == 1) { \
        int _idx = 3264 + lane; \
        GLD_LDS(_src + (size_t)_idx * 16, _dst + (size_t)_idx * 16); \
    } \
} while (0)

// retire exactly the previous chunk's loads (per-wave issue counts differ)
#define WAITCHUNK() do { \
    if (w == 1) { WAITV(18); } else { WAITV(17); } \
} while (0)

    if (w > 0) {
        STAGE_DP(0);                 // wave1: 18, waves2/3: 17 outstanding
        STAGE_DP(1);                 // 36 / 34
        WAITCHUNK();                 // chunk 0 landed (chunk 1 in flight)
    }
    __builtin_amdgcn_s_barrier();
    __builtin_amdgcn_sched_barrier(0);

    for (int ch = 0; ch < C; ch++) {
        if (w > 0) {
            if (ch + 2 < C) {
                STAGE_DP(ch + 2);    // issue next-next chunk
                WAITCHUNK();         // chunk ch+1 landed; ch+2 in flight
            } else {
                WAITV(0);            // tail: drain whatever remains
            }
        } else {
            const float* bb = emS[ch % 3];
            const int t0 = 64 * ch + 1;
            const int soff = 4 * lane;
            if (t0 + 63 <= t_stop) {
                // ---- fast path: 32 fused pairs, 2 b128 reads each ----
                f32x4 e = *(const f32x4*)&bb[0 * 208 + soff];
                f32x4 f = *(const f32x4*)&bb[1 * 208 + soff];
                #pragma unroll
                for (int k = 0; k < 32; k++) {
                    f32x4 en = (f32x4){0.f,0.f,0.f,0.f};
                    f32x4 fn = (f32x4){0.f,0.f,0.f,0.f};
                    if (k < 31) {
                        en = *(const f32x4*)&bb[(2 * k + 2) * 208 + soff];
                        fn = *(const f32x4*)&bb[(2 * k + 3) * 208 + soff];
                    }
                    float pht = shup1(e[3]);
                    float h1 = shup1(a3);
                    float h2 = shup1(a2);
                    float h3 = shup1(a1);
                    float tm1 = fmaf(kH, h3, h1 + h2);
                    float t0v = a0 + h1;
                    float t1v = fmaf(kA, h1, a1 + a0);
                    float t2v = a2 + a1;
                    float t3v = fmaf(kB, a1, a3 + a2);
                    float um1 = pht * tm1;
                    float u0 = e[0] * t0v, u1 = e[1] * t1v;
                    float u2 = e[2] * t2v, u3 = e[3] * t3v;
                    a0 = (f[0] * (u0 + um1)) * m0;
                    a1 = (f[1] * fmaf(kA, um1, u1 + u0)) * m13;
                    a2 = (f[2] * (u2 + u1)) * m13;
                    a3 = (f[3] * fmaf(kB, u1, u3 + u2)) * m13;
                    if ((k & 7) == 7) {
                        int tc = t0 + 2 * k + 1;
                        float lm = fmaxf(fmaxf(a0, a1), fmaxf(a2, a3));
                        int sa1 = (2 * L < tc) ? 2 * L : tc;
                        int sa2 = (int)(2.0f * L * tc / hl);
                        float v1 = __shfl(lm, sa1 >> 2);
                        float v2 = __shfl(lm, sa2 >> 2);
                        float av = fmaxf(v1, v2);
                        int eb = (__float_as_int(av) >> 23) & 0xFF;
                        if (eb != 0 && eb != 255) {
                            int e2i = eb - 127;
                            kacc += e2i;
                            float sc = __int_as_float((127 - e2i) << 23);
                            a0 *= sc; a1 *= sc; a2 *= sc; a3 *= sc;
                        }
                    }
                    e = en; f = fn;
                }
            } else {
                // ---- slow tail: single steps ----
                for (int t = t0; t <= t_stop; t++) {
                    if ((t & 15) == 0) {
                        float lm = fmaxf(fmaxf(a0, a1), fmaxf(a2, a3));
                        int sa1 = (2 * L < t) ? 2 * L : t;
                        int sa2 = (int)(2.0f * L * t / hl);
                        float v1 = __shfl(lm, sa1 >> 2);
                        float v2 = __shfl(lm, sa2 >> 2);
                        float av = fmaxf(v1, v2);
                        int eb = (__float_as_int(av) >> 23) & 0xFF;
                        if (eb != 0 && eb != 255) {
                            int e2i = eb - 127;
                            kacc += e2i;
                            float sc = __int_as_float((127 - e2i) << 23);
                            a0 *= sc; a1 *= sc; a2 *= sc; a3 *= sc;
                        }
                    }
                    f32x4 e = *(const f32x4*)&bb[(t - t0) * 208 + soff];
                    float p3 = shup1(a3);
                    float n0 = (a0 + p3) * e[0];
                    float n1 = fmaf(kA, p3, a1 + a0) * e[1];
                    float n2 = (a2 + a1) * e[2];
                    float n3 = fmaf(kB, a1, a3 + a2) * e[3];
                    a0 = n0 * m0; a1 = n1 * m13; a2 = n2 * m13; a3 = n3 * m13;
                }
            }
        }
        __builtin_amdgcn_s_barrier();
        __builtin_amdgcn_sched_barrier(0);
    }
#undef STAGE_DP
#undef WAITCHUNK

    if (w == 0) {
        sA[lane * 4 + 0] = a0; sA[lane * 4 + 1] = a1;
        sA[lane * 4 + 2] = a2; sA[lane * 4 + 3] = a3;
    }
    __syncthreads();

    if (tid == 0) {
        int idx = 2 * L;
        float s = sA[idx] + sA[idx - 1];
        float la = __logf(s) + (float)(kacc - 11 * hl) * LN2F;
        float loss = -la;
        if (!isfinite(loss) || loss >= 1e29f) loss = 0.0f;
        atomicAdd(out, loss * 0.0625f);
    }
}

// ---------------------------------------------------------------------------
extern "C" void kernel_launch(void* const* d_in, const int* in_sizes, int n_in,
                              void* d_out, int out_size, void* d_ws, size_t ws_size,
                              hipStream_t stream)
{
    const float* hs    = (const float*)d_in[0];   // [16,800,512]
    const float* W     = (const float*)d_in[1];   // [512,4000]
    const float* bias  = (const float*)d_in[2];   // [4000]
    const int*   hlens = (const int*)d_in[3];     // [16]
    const int*   ys    = (const int*)d_in[4];     // [16,100]
    const int*   ylens = (const int*)d_in[5];     // [16]
    float* out = (float*)d_out;

    // workspace layout (bytes)
    char* wsb = (char*)d_ws;
    short* W2      = (short*)(wsb);                         // 4,194,304
    short* A2      = (short*)(wsb + 4194304);               // 13,107,200
    float* PE      = (float*)(wsb + 4194304);               // overlays A2 after lse_mfma: 10,649,600 (+slack)
    float* biasp   = (float*)(wsb + 17301504);              // 16,384
    __hip_bfloat16* Praw = (__hip_bfloat16*)(wsb + 17317888); // 3,276,800
    float* lse_sum = (float*)(wsb + 20594688);              // 51,200
    unsigned char* M     = (unsigned char*)(wsb + 20645888);// 65,536
    unsigned char* canon = (unsigned char*)(wsb + 20711424);// 2,048
    // total ~20.7 MB

    hipLaunchKernelGGL(prep,     dim3(4241), dim3(256), 0, stream,
                       hs, W, bias, ys, W2, A2, biasp, M, canon, lse_sum, out);
    hipLaunchKernelGGL(lse_mfma, dim3(1664), dim3(512), 0, stream,
                       A2, W2, biasp, M, lse_sum, Praw);
    hipLaunchKernelGGL(pexp,     dim3(800),  dim3(256), 0, stream,
                       Praw, lse_sum, canon, PE);
    hipLaunchKernelGGL(ctc_dp,   dim3(16),   dim3(256), 0, stream,
                       PE, hlens, ys, ylens, out);
}

// Round 15
// 179.938 us; speedup vs baseline: 1.1182x; 1.1182x over previous
//
#include <hip/hip_runtime.h>
#include <hip/hip_bf16.h>
#include <math.h>

#define NEGV -1e30f
#define LN2F 0.6931471805599453f

// B=16, T=800, D=512, V=4000 (padded to 4096), Lmax=100, S=201
// M = B*T = 12800 rows.
// R15: GEMM operands are FP8 e4m3 (OCP), stored pre-swizzled in PAIRED
// fragment order (K-step pairs share one 16-B word so fragment loads stay
// ds_read_b128):
//   A2[rb<100][p<8][wm<2][mi<4][lane<64][16B]  bytes 0-7: it=2p, 8-15: it=2p+1
//   W2[ct<32][p<8][wn<2][ni<4][lane<64][16B]   (W pre-scaled x32; acc * 1/32)
// element j of each 8-byte half: k = p*64 + sub*32 + (lane>>4)*8 + j,
// row/col = tile0 + slot*16 + (lane&15). Chunk (tile,p) = contiguous 8 KB.

typedef __attribute__((ext_vector_type(8))) short bf16x8;
typedef __attribute__((ext_vector_type(4))) float f32x4;
typedef __attribute__((ext_vector_type(2))) long longx2;

__device__ __forceinline__ short f2bf(float x) {
    __hip_bfloat16 h = __float2bfloat16(x);
    return __builtin_bit_cast(short, h);
}

// pack 4 floats -> 4 fp8 e4m3 bytes (HW cvt, OCP on gfx950)
__device__ __forceinline__ int pk4(float a, float b, float c, float d) {
    int v = 0;
    v = __builtin_amdgcn_cvt_pk_fp8_f32(a, b, v, false);  // bytes 0,1
    v = __builtin_amdgcn_cvt_pk_fp8_f32(c, d, v, true);   // bytes 2,3
    return v;
}

// wave-wide shift-up-by-1 with zero fill on the VALU (DPP wave_shr:1)
__device__ __forceinline__ float shup1(float x) {
    return __builtin_bit_cast(float,
        __builtin_amdgcn_update_dpp(0, __builtin_bit_cast(int, x),
                                    0x138, 0xf, 0xf, true));
}

#define GLD_LDS(g, l) \
    __builtin_amdgcn_global_load_lds( \
        (const __attribute__((address_space(1))) void*)(g), \
        (__attribute__((address_space(3))) void*)(l), 16, 0, 0)

// counted drain + full scheduling fence (rule #18)
#define WAITV(n) do { \
    asm volatile("s_waitcnt vmcnt(" #n ")" ::: "memory"); \
    __builtin_amdgcn_sched_barrier(0); \
} while (0)

// ---------------------------------------------------------------------------
// prep: blocks 0..511 W->fp8 swizzle (64-col x 64-k tiles); 512..2111
// hs->fp8 A swizzle; 2112..2127 per-batch tables (16-way parallel);
// 2128 biasp/lse_sum/out init. grid 2129 x 256.
// ---------------------------------------------------------------------------
__global__ __launch_bounds__(256) void prep(
    const float* __restrict__ hs, const float* __restrict__ W,
    const float* __restrict__ bias, const int* __restrict__ ys,
    short* __restrict__ W2, short* __restrict__ A2,
    float* __restrict__ biasp, unsigned char* __restrict__ M,
    unsigned char* __restrict__ canon, float* __restrict__ lse_sum,
    float* __restrict__ out)
{
    __shared__ float tile[64][65];
    __shared__ unsigned char mapl[4096];
    const int bx = blockIdx.x, tid = threadIdx.x;

    if (bx < 512) {
        // ---- W [512][4000] -> W2 fp8 paired layout, scaled x32 ----
        const int n0g = bx & 63;           // 64-col group
        const int p   = bx >> 6;           // 0..7 (64-k group)
        const int k0  = p * 64;
        #pragma unroll
        for (int q = 0; q < 16; q++) {
            int idx = q * 256 + tid;
            int k = idx >> 6, n = idx & 63;
            int gn = n0g * 64 + n;
            tile[k][n] = (gn < 4000) ? W[(size_t)(k0 + k) * 4000 + gn] * 32.0f
                                     : 0.0f;
        }
        __syncthreads();
        const int nn = tid >> 6, lane = tid & 63;
        const int l16 = lane & 15, quad = lane >> 4;
        const int ct = n0g >> 1, wn = n0g & 1;
        const int c = nn * 16 + l16;
        float f0[8], f1[8];
        #pragma unroll
        for (int j = 0; j < 8; j++) {
            f0[j] = tile[quad * 8 + j][c];        // sub0: it=2p
            f1[j] = tile[32 + quad * 8 + j][c];   // sub1: it=2p+1
        }
        int4 o;
        o.x = pk4(f0[0], f0[1], f0[2], f0[3]);
        o.y = pk4(f0[4], f0[5], f0[6], f0[7]);
        o.z = pk4(f1[0], f1[1], f1[2], f1[3]);
        o.w = pk4(f1[4], f1[5], f1[6], f1[7]);
        size_t chunk = ((((size_t)ct * 8 + p) * 2 + wn) * 4 + nn) * 64 + lane;
        *(int4*)(W2 + chunk * 8) = o;
    } else if (bx < 2112) {
        // ---- hs fp32 -> A2 fp8 paired layout ----
        int g = (bx - 512) * 256 + tid;            // 0..409599
        int lane = g & 63, mi = (g >> 6) & 3, wm = (g >> 8) & 1;
        int p = (g >> 9) & 7, rb = g >> 12;
        int row = rb * 128 + wm * 64 + mi * 16 + (lane & 15);
        int kb = p * 64 + (lane >> 4) * 8;
        const float* src = hs + (size_t)row * 512 + kb;
        float4 u  = *(const float4*)src;
        float4 v  = *(const float4*)(src + 4);
        float4 u2 = *(const float4*)(src + 32);
        float4 v2 = *(const float4*)(src + 36);
        int4 o;
        o.x = pk4(u.x,  u.y,  u.z,  u.w);
        o.y = pk4(v.x,  v.y,  v.z,  v.w);
        o.z = pk4(u2.x, u2.y, u2.z, u2.w);
        o.w = pk4(v2.x, v2.y, v2.z, v2.w);
        *(int4*)(A2 + (size_t)g * 8) = o;
    } else if (bx < 2128) {
        // ---- tables for batch b = bx - 2112 (16-way parallel) ----
        const int b = bx - 2112;
        for (int i = tid; i < 1024; i += 256)
            ((unsigned int*)mapl)[i] = 0xFFFFFFFFu;
        __syncthreads();
        if (tid == 0) mapl[0] = 0;
        __syncthreads();
        if (tid < 100) mapl[ys[b * 100 + tid]] = (unsigned char)(tid + 1);
        __syncthreads();
        for (int i = tid; i < 1024; i += 256)
            ((unsigned int*)(M + (size_t)b * 4096))[i] = ((const unsigned int*)mapl)[i];
        if (tid < 128) {
            int colc = (tid >= 1 && tid <= 100) ? ys[b * 100 + tid - 1] : 0;
            canon[b * 128 + tid] = mapl[colc];
        }
    } else {
        // ---- biasp / lse_sum / out init ----
        for (int i = tid; i < 4096; i += 256)
            biasp[i] = (i < 4000) ? bias[i] : NEGV;
        for (int i = tid; i < 12800; i += 256)
            lse_sum[i] = 0.0f;
        if (tid == 0) out[0] = 0.0f;
    }
}

// ---------------------------------------------------------------------------
// Streaming-sumexp GEMM, R15: fp8 e4m3 operands, paired-K fragments.
// Structure = R13-proven skeleton at half the LDS bytes: 128x256 tile,
// 8 waves of 64x64, 3 rotating 24-KB buffers, each buffer = one K-PAIR
// (A 8 KB + B0 8 KB + B1 8 KB), 24 lane-linear 1-KB segments (wave owns 3),
// steady-state WAITV(3), 8 barriers. Per pair: 8 ds_read_b128 -> 32 MFMA
// (fp8 16x16x32, bf16 rate). Epilogue: acc * (1/32) undoes W prescale.
// grid 1664 x 512, LDS 72 KB, 2 blocks/CU.
// ---------------------------------------------------------------------------
__global__ __launch_bounds__(512, 4) void lse_mfma(
    const short* __restrict__ A2,     // fp8 paired fragment layout
    const short* __restrict__ W2,     // fp8 paired fragment layout (x32)
    const float* __restrict__ biasp,  // [4096]
    const unsigned char* __restrict__ M,  // [16][4096]
    float* __restrict__ lse_sum,      // [12800]
    __hip_bfloat16* __restrict__ Praw)// [12800][128]
{
    const unsigned int bid = blockIdx.x;
    const unsigned int xcd = bid & 7;
    const unsigned int s = bid >> 3;       // 0..207
    const unsigned int cp = s / 13;        // 0..15  (slow: 256-col tile)
    const unsigned int rl = s - cp * 13;   // 0..12  (fast: row tile within XCD)
    const unsigned int rb = rl * 8 + xcd;  // 0..103
    if (rb >= 100) return;

    const int tid = threadIdx.x;
    const int w = tid >> 6, lane = tid & 63;   // w = 0..7
    const int quad = lane >> 4, l16 = lane & 15;
    const int wm = w >> 2;                 // 0..1: 64-row half
    const int wc = w & 3;                  // 0..3: 64-col slot
    const int row0 = rb * 128;
    const int col0 = cp * 256;

    // 3 rotating staging buffers: [A 4096][B0 4096][B1 4096] shorts (24 KB)
    __shared__ __align__(16) short sbuf[3][12288];

    // staging: 24 x 1-KB segments per pair; wave w owns segments 3w..3w+2.
    // chunk (tile, p) = 4096 shorts; p-stride = 4096 shorts.
    const short* gb[3];
    int lo[3];
    #pragma unroll
    for (int j = 0; j < 3; j++) {
        int sg = 3 * w + j;
        const short* cbase =
            (sg < 8)  ? (A2 + (size_t)rb * 32768)
          : (sg < 16) ? (W2 + (size_t)(2 * cp) * 32768)
                      : (W2 + (size_t)(2 * cp + 1) * 32768);
        gb[j] = cbase + (sg & 7) * 512 + lane * 8;
        lo[j] = sg * 512 + lane * 8;
    }

#define STAGE(p_, bi_) do { \
    GLD_LDS(gb[0] + (size_t)(p_) * 4096, &sbuf[bi_][lo[0]]); \
    GLD_LDS(gb[1] + (size_t)(p_) * 4096, &sbuf[bi_][lo[1]]); \
    GLD_LDS(gb[2] + (size_t)(p_) * 4096, &sbuf[bi_][lo[2]]); \
} while (0)

    f32x4 acc[4][4];
    #pragma unroll
    for (int mi = 0; mi < 4; mi++)
        #pragma unroll
        for (int ni = 0; ni < 4; ni++) acc[mi][ni] = (f32x4){0.f,0.f,0.f,0.f};

    STAGE(0, 0);                       // 3 outstanding
    STAGE(1, 1);                       // 6 outstanding
    WAITV(3);                          // pair0 landed (pair1 in flight)
    __builtin_amdgcn_s_barrier();
    __builtin_amdgcn_sched_barrier(0);

    const int boff = 4096 + (wc >> 1) * 4096 + (wc & 1) * 2048;

    #pragma unroll
    for (int p = 0; p < 8; ++p) {
        if (p + 2 < 8) STAGE(p + 2, (p + 2) % 3);

        const short* cb = &sbuf[p % 3][0];
        const short* ap = cb + wm * 2048 + lane * 8;     // + mi*512
        const short* bp = cb + boff + lane * 8;          // + ni*512
        longx2 af[4], bf[4];
        #pragma unroll
        for (int mi = 0; mi < 4; mi++) af[mi] = *(const longx2*)(ap + mi * 512);
        #pragma unroll
        for (int ni = 0; ni < 4; ni++) bf[ni] = *(const longx2*)(bp + ni * 512);

        __builtin_amdgcn_s_setprio(1);
        #pragma unroll
        for (int mi = 0; mi < 4; mi++)
            #pragma unroll
            for (int ni = 0; ni < 4; ni++)
                acc[mi][ni] = __builtin_amdgcn_mfma_f32_16x16x32_fp8_fp8(
                    af[mi][0], bf[ni][0], acc[mi][ni], 0, 0, 0);
        #pragma unroll
        for (int mi = 0; mi < 4; mi++)
            #pragma unroll
            for (int ni = 0; ni < 4; ni++)
                acc[mi][ni] = __builtin_amdgcn_mfma_f32_16x16x32_fp8_fp8(
                    af[mi][1], bf[ni][1], acc[mi][ni], 0, 0, 0);
        __builtin_amdgcn_s_setprio(0);

        if (p < 7) {
            if (p < 6) { WAITV(3); }  // pair(p+1) landed; pair(p+2) in flight
            else       { WAITV(0); }  // tail: pair(7) landed
            __builtin_amdgcn_s_barrier();
            __builtin_amdgcn_sched_barrier(0);
        }
    }
#undef STAGE
    __builtin_amdgcn_sched_barrier(0);   // keep epilogue VMEM out of the loop

    // epilogue: undo W prescale, sumexp partials + scatter label logits
    const int b0i = row0 / 800;
    const int b1i = (b0i + 1 < 16) ? b0i + 1 : 15;
    const int bbound = (b0i + 1) * 800;
    float sv[16];
    #pragma unroll
    for (int i = 0; i < 16; i++) sv[i] = 0.0f;
    #pragma unroll
    for (int ni = 0; ni < 4; ni++) {
        int col = col0 + wc * 64 + ni * 16 + l16;
        float bj = biasp[col];
        unsigned char sl0 = M[(size_t)b0i * 4096 + col];
        unsigned char sl1 = M[(size_t)b1i * 4096 + col];
        #pragma unroll
        for (int mi = 0; mi < 4; mi++) {
            #pragma unroll
            for (int r = 0; r < 4; r++) {
                int row = row0 + wm * 64 + mi * 16 + quad * 4 + r;
                float v = acc[mi][ni][r] * 0.03125f + bj;
                sv[mi * 4 + r] += __expf(v);
                unsigned char sl = (row < bbound) ? sl0 : sl1;
                if (sl != 255)
                    Praw[(size_t)row * 128 + sl] = __float2bfloat16(v);
            }
        }
    }
    #pragma unroll
    for (int off = 1; off < 16; off <<= 1)
        #pragma unroll
        for (int i = 0; i < 16; i++) sv[i] += __shfl_xor(sv[i], off);
    if (l16 == 0) {
        #pragma unroll
        for (int mi = 0; mi < 4; mi++)
            #pragma unroll
            for (int r = 0; r < 4; r++)
                atomicAdd(&lse_sum[row0 + wm * 64 + mi * 16 + quad * 4 + r],
                          sv[mi * 4 + r]);
    }
}

// ---------------------------------------------------------------------------
// pexp (R5-proven): PE[row][s] = exp(Praw[row][st[s]]) * rcp(lse) * 2^11.
// ---------------------------------------------------------------------------
__global__ __launch_bounds__(256) void pexp(
    const __hip_bfloat16* __restrict__ Praw,  // [12800][128]
    const float* __restrict__ lse_sum,        // [12800]
    const unsigned char* __restrict__ canon,  // [16][128]
    float* __restrict__ PE)                   // [12800][208]
{
    __shared__ unsigned char st[224];
    __shared__ float scs[16];
    const int bp = blockIdx.x;           // 0..799
    const int b = bp / 50, rr = bp - b * 50;
    const int tid = threadIdx.x;
    const unsigned char* cb = canon + b * 128;
    if (tid < 224) {
        int idx = (tid + 1) >> 1;
        st[tid] = (tid & 1) ? cb[idx < 128 ? idx : 127] : (unsigned char)0;
    }
    const int row0 = b * 800 + rr * 16;
    if (tid < 16) scs[tid] = __builtin_amdgcn_rcpf(lse_sum[row0 + tid]) * 2048.0f;
    __syncthreads();
    for (int item = tid; item < 832; item += 256) {   // 16 rows x 52 float4
        int i = item / 52, sg = item - i * 52;
        int row = row0 + i;
        const __hip_bfloat16* pr = Praw + (size_t)row * 128;
        float sc = scs[i];
        int s0 = sg * 4;
        float4 o;
        o.x = (s0 + 0 <= 200) ? __expf(__bfloat162float(pr[st[s0 + 0]])) * sc : 0.f;
        o.y = (s0 + 1 <= 200) ? __expf(__bfloat162float(pr[st[s0 + 1]])) * sc : 0.f;
        o.z = (s0 + 2 <= 200) ? __expf(__bfloat162float(pr[st[s0 + 2]])) * sc : 0.f;
        o.w = (s0 + 3 <= 200) ? __expf(__bfloat162float(pr[st[s0 + 3]])) * sc : 0.f;
        *(float4*)&PE[(size_t)row * 208 + s0] = o;
    }
}

// ---------------------------------------------------------------------------
// ctc_dp (R9-proven): CTC forward DP, 3-buffer rotating PE->LDS staging with
// counted vmcnt, 2 chunks ahead. All global_load_lds full-exec and
// lane-linear (m104 HW rule). Waves 2,3: 17 loads/chunk; wave 1: 18.
// Drains: wave1 WAITV(18), waves2/3 WAITV(17); never 0 until tail.
// ---------------------------------------------------------------------------
__global__ __launch_bounds__(256) void ctc_dp(
    const float* __restrict__ PE,             // [12800][208]
    const int* __restrict__ hlens,
    const int* __restrict__ ys,
    const int* __restrict__ ylens,
    float* __restrict__ out)
{
    const int b = blockIdx.x, tid = threadIdx.x;
    const int w = tid >> 6, lane = tid & 63;
    __shared__ float emS[3][13376];   // 3 x (64 rows x 208 + pad)
    __shared__ float sA[256];

    const float* Pb = PE + (size_t)b * 800 * 208;
    const int hl = hlens[b], L = ylens[b];
    const int t_stop = hl - 1;
    const int C = (t_stop + 63) >> 6;

    const int yb = b * 100;
    float kA = 0.f, kB = 0.f, kH = 0.f;
    if (lane >= 1 && 2 * lane <= 99)
        kA = (ys[yb + 2 * lane] != ys[yb + 2 * lane - 1]) ? 1.f : 0.f;
    if (2 * lane + 1 <= 99)
        kB = (ys[yb + 2 * lane + 1] != ys[yb + 2 * lane]) ? 1.f : 0.f;
    if (lane >= 1 && 2 * lane - 1 <= 99)
        kH = (ys[yb + 2 * lane - 1] != ys[yb + 2 * lane - 2]) ? 1.f : 0.f;
    const float m0  = (lane <= 50) ? 1.f : 0.f;
    const float m13 = (lane <= 49) ? 1.f : 0.f;

    float a0 = 0.f, a1 = 0.f, a2 = 0.f, a3 = 0.f;
    if (w == 0 && lane == 0) {
        a0 = Pb[0];
        a1 = Pb[1];
    }
    int kacc = 0;

    // staging: waves 1-3 (192 threads). All loads full-exec, lane-linear.
#define STAGE_DP(nc_) do { \
    const char* _src = (const char*)(Pb + (size_t)(64 * (nc_) + 1) * 208); \
    char* _dst = (char*)&emS[(nc_) % 3][0]; \
    const int _base = tid - 64; \
    _Pragma("unroll") \
    for (int _j = 0; _j < 17; _j++) { \
        int _idx = _base + 192 * _j; \
        GLD_LDS(_src + (size_t)_idx * 16, _dst + (size_t)_idx * 16); \
    } \
    if (w == 1) { \
        int _idx = 3264 + lane; \
        GLD_LDS(_src + (size_t)_idx * 16, _dst + (size_t)_idx * 16); \
    } \
} while (0)

// retire exactly the previous chunk's loads (per-wave issue counts differ)
#define WAITCHUNK() do { \
    if (w == 1) { WAITV(18); } else { WAITV(17); } \
} while (0)

    if (w > 0) {
        STAGE_DP(0);                 // wave1: 18, waves2/3: 17 outstanding
        STAGE_DP(1);                 // 36 / 34
        WAITCHUNK();                 // chunk 0 landed (chunk 1 in flight)
    }
    __builtin_amdgcn_s_barrier();
    __builtin_amdgcn_sched_barrier(0);

    for (int ch = 0; ch < C; ch++) {
        if (w > 0) {
            if (ch + 2 < C) {
                STAGE_DP(ch + 2);    // issue next-next chunk
                WAITCHUNK();         // chunk ch+1 landed; ch+2 in flight
            } else {
                WAITV(0);            // tail: drain whatever remains
            }
        } else {
            const float* bb = emS[ch % 3];
            const int t0 = 64 * ch + 1;
            const int soff = 4 * lane;
            if (t0 + 63 <= t_stop) {
                // ---- fast path: 32 fused pairs, 2 b128 reads each ----
                f32x4 e = *(const f32x4*)&bb[0 * 208 + soff];
                f32x4 f = *(const f32x4*)&bb[1 * 208 + soff];
                #pragma unroll
                for (int k = 0; k < 32; k++) {
                    f32x4 en = (f32x4){0.f,0.f,0.f,0.f};
                    f32x4 fn = (f32x4){0.f,0.f,0.f,0.f};
                    if (k < 31) {
                        en = *(const f32x4*)&bb[(2 * k + 2) * 208 + soff];
                        fn = *(const f32x4*)&bb[(2 * k + 3) * 208 + soff];
                    }
                    float pht = shup1(e[3]);
                    float h1 = shup1(a3);
                    float h2 = shup1(a2);
                    float h3 = shup1(a1);
                    float tm1 = fmaf(kH, h3, h1 + h2);
                    float t0v = a0 + h1;
                    float t1v = fmaf(kA, h1, a1 + a0);
                    float t2v = a2 + a1;
                    float t3v = fmaf(kB, a1, a3 + a2);
                    float um1 = pht * tm1;
                    float u0 = e[0] * t0v, u1 = e[1] * t1v;
                    float u2 = e[2] * t2v, u3 = e[3] * t3v;
                    a0 = (f[0] * (u0 + um1)) * m0;
                    a1 = (f[1] * fmaf(kA, um1, u1 + u0)) * m13;
                    a2 = (f[2] * (u2 + u1)) * m13;
                    a3 = (f[3] * fmaf(kB, u1, u3 + u2)) * m13;
                    if ((k & 7) == 7) {
                        int tc = t0 + 2 * k + 1;
                        float lm = fmaxf(fmaxf(a0, a1), fmaxf(a2, a3));
                        int sa1 = (2 * L < tc) ? 2 * L : tc;
                        int sa2 = (int)(2.0f * L * tc / hl);
                        float v1 = __shfl(lm, sa1 >> 2);
                        float v2 = __shfl(lm, sa2 >> 2);
                        float av = fmaxf(v1, v2);
                        int eb = (__float_as_int(av) >> 23) & 0xFF;
                        if (eb != 0 && eb != 255) {
                            int e2i = eb - 127;
                            kacc += e2i;
                            float sc = __int_as_float((127 - e2i) << 23);
                            a0 *= sc; a1 *= sc; a2 *= sc; a3 *= sc;
                        }
                    }
                    e = en; f = fn;
                }
            } else {
                // ---- slow tail: single steps ----
                for (int t = t0; t <= t_stop; t++) {
                    if ((t & 15) == 0) {
                        float lm = fmaxf(fmaxf(a0, a1), fmaxf(a2, a3));
                        int sa1 = (2 * L < t) ? 2 * L : t;
                        int sa2 = (int)(2.0f * L * t / hl);
                        float v1 = __shfl(lm, sa1 >> 2);
                        float v2 = __shfl(lm, sa2 >> 2);
                        float av = fmaxf(v1, v2);
                        int eb = (__float_as_int(av) >> 23) & 0xFF;
                        if (eb != 0 && eb != 255) {
                            int e2i = eb - 127;
                            kacc += e2i;
                            float sc = __int_as_float((127 - e2i) << 23);
                            a0 *= sc; a1 *= sc; a2 *= sc; a3 *= sc;
                        }
                    }
                    f32x4 e = *(const f32x4*)&bb[(t - t0) * 208 + soff];
                    float p3 = shup1(a3);
                    float n0 = (a0 + p3) * e[0];
                    float n1 = fmaf(kA, p3, a1 + a0) * e[1];
                    float n2 = (a2 + a1) * e[2];
                    float n3 = fmaf(kB, a1, a3 + a2) * e[3];
                    a0 = n0 * m0; a1 = n1 * m13; a2 = n2 * m13; a3 = n3 * m13;
                }
            }
        }
        __builtin_amdgcn_s_barrier();
        __builtin_amdgcn_sched_barrier(0);
    }
#undef STAGE_DP
#undef WAITCHUNK

    if (w == 0) {
        sA[lane * 4 + 0] = a0; sA[lane * 4 + 1] = a1;
        sA[lane * 4 + 2] = a2; sA[lane * 4 + 3] = a3;
    }
    __syncthreads();

    if (tid == 0) {
        int idx = 2 * L;
        float s = sA[idx] + sA[idx - 1];
        float la = __logf(s) + (float)(kacc - 11 * hl) * LN2F;
        float loss = -la;
        if (!isfinite(loss) || loss >= 1e29f) loss = 0.0f;
        atomicAdd(out, loss * 0.0625f);
    }
}

// ---------------------------------------------------------------------------
extern "C" void kernel_launch(void* const* d_in, const int* in_sizes, int n_in,
                              void* d_out, int out_size, void* d_ws, size_t ws_size,
                              hipStream_t stream)
{
    const float* hs    = (const float*)d_in[0];   // [16,800,512]
    const float* W     = (const float*)d_in[1];   // [512,4000]
    const float* bias  = (const float*)d_in[2];   // [4000]
    const int*   hlens = (const int*)d_in[3];     // [16]
    const int*   ys    = (const int*)d_in[4];     // [16,100]
    const int*   ylens = (const int*)d_in[5];     // [16]
    float* out = (float*)d_out;

    // workspace layout (bytes)
    char* wsb = (char*)d_ws;
    short* W2      = (short*)(wsb);                         // fp8: 2,097,152
    short* A2      = (short*)(wsb + 4194304);               // fp8: 6,553,600
    float* PE      = (float*)(wsb + 4194304);               // overlays A2 after lse_mfma: 10,649,600 (+slack)
    float* biasp   = (float*)(wsb + 17301504);              // 16,384
    __hip_bfloat16* Praw = (__hip_bfloat16*)(wsb + 17317888); // 3,276,800
    float* lse_sum = (float*)(wsb + 20594688);              // 51,200
    unsigned char* M     = (unsigned char*)(wsb + 20645888);// 65,536
    unsigned char* canon = (unsigned char*)(wsb + 20711424);// 2,048
    // total ~20.7 MB

    hipLaunchKernelGGL(prep,     dim3(2129), dim3(256), 0, stream,
                       hs, W, bias, ys, W2, A2, biasp, M, canon, lse_sum, out);
    hipLaunchKernelGGL(lse_mfma, dim3(1664), dim3(512), 0, stream,
                       A2, W2, biasp, M, lse_sum, Praw);
    hipLaunchKernelGGL(pexp,     dim3(800),  dim3(256), 0, stream,
                       Praw, lse_sum, canon, PE);
    hipLaunchKernelGGL(ctc_dp,   dim3(16),   dim3(256), 0, stream,
                       PE, hlens, ys, ylens, out);
}